// Round 14
// baseline (2361.301 us; speedup 1.0000x reference)
//
#include <hip/hip_runtime.h>
#include <hip/hip_bf16.h>

// DeeperGCN on MI355X — round 14: k_agg FUSED into the MFMA GEMM. Each 64-row block
// aggregates its dst rows (scattered P gathers, bond-emb, BN, VN) straight into the
// XOR-swizzled LDS A-tile (bf16 = same rounding as the old T store), then MFMAs.
// T round-trip eliminated; P ping-pongs between two buffers (no in-place race).
// N=150000, E=300000, G=4096, H=256, L=7.

#define Ncnt 150000
#define Ecnt 300000
#define Gcnt 4096
#define Hc 256
#define Lcnt 7
#define BN_EPS 1e-5f
#define MSG_EPS 1e-7f

typedef __hip_bfloat16 bf16;
typedef __attribute__((ext_vector_type(8))) short bf16x8;
typedef __attribute__((ext_vector_type(8))) unsigned short u16x8;
typedef __attribute__((ext_vector_type(4))) float f32x4;

static __device__ __forceinline__ int imin(int a, int b) { return a < b ? a : b; }

static __device__ __forceinline__ float bs2f(unsigned short s) {
  unsigned u = ((unsigned)s) << 16;
  union { unsigned u; float f; } c; c.u = u; return c.f;
}
static __device__ __forceinline__ unsigned short f2bs(float f) {
  bf16 h = __float2bfloat16(f);
  union { bf16 h; unsigned short s; } c; c.h = h; return c.s;
}
static __device__ __forceinline__ float4 bf4tof4(ushort4 u) {
  float4 r; r.x = bs2f(u.x); r.y = bs2f(u.y); r.z = bs2f(u.z); r.w = bs2f(u.w); return r;
}
static __device__ __forceinline__ ushort4 f4tobf4(float4 v) {
  ushort4 u; u.x = f2bs(v.x); u.y = f2bs(v.y); u.z = f2bs(v.z); u.w = f2bs(v.w); return u;
}

__global__ __launch_bounds__(256) void k_zero(float* __restrict__ p, int n) {
  int i = blockIdx.x * 256 + threadIdx.x;
  if (i < n) p[i] = 0.f;
}
__global__ __launch_bounds__(256) void k_zero_int(int* __restrict__ p, int n) {
  int i = blockIdx.x * 256 + threadIdx.x;
  if (i < n) p[i] = 0;
}
__global__ void k_diag(float* __restrict__ out, float v) { out[0] = v; }

// ---- BN scale/bias precompute + stats recycle ----
__global__ __launch_bounds__(256) void k_bnprep(float* __restrict__ stats,
                                                const float* __restrict__ gamma, const float* __restrict__ beta,
                                                float* __restrict__ scb, float* __restrict__ bbb, float invM) {
  int c = threadIdx.x;
  float mu = stats[c] * invM;
  float var = stats[Hc + c] * invM - mu * mu;
  float sc = rsqrtf(var + BN_EPS) * gamma[c];
  scb[c] = sc;
  bbb[c] = beta[c] - mu * sc;
  stats[c] = 0.f;
  stats[Hc + c] = 0.f;
}

// ---- CSR build (counting sort by dst) ----
__global__ __launch_bounds__(256) void k_count(const int* __restrict__ ei, int* __restrict__ cnt) {
  int e = blockIdx.x * 256 + threadIdx.x;
  if (e < Ecnt) atomicAdd(&cnt[ei[Ecnt + e]], 1);
}
__global__ __launch_bounds__(256) void k_scan1(const int* __restrict__ cnt, int* __restrict__ rowptr,
                                               int* __restrict__ bsum, int n) {
  __shared__ int sh[256];
  int t = threadIdx.x;
  int i = blockIdx.x * 256 + t;
  int v = (i < n) ? cnt[i] : 0;
  sh[t] = v;
  __syncthreads();
#pragma unroll
  for (int off = 1; off < 256; off <<= 1) {
    int u = (t >= off) ? sh[t - off] : 0;
    __syncthreads();
    sh[t] += u;
    __syncthreads();
  }
  if (i < n) rowptr[i] = sh[t] - v;
  if (t == 255) bsum[blockIdx.x] = sh[255];
}
__global__ __launch_bounds__(1024) void k_scan2(int* __restrict__ bsum, int nb) {
  __shared__ int sh[1024];
  int t = threadIdx.x;
  int v = (t < nb) ? bsum[t] : 0;
  sh[t] = v;
  __syncthreads();
#pragma unroll
  for (int off = 1; off < 1024; off <<= 1) {
    int u = (t >= off) ? sh[t - off] : 0;
    __syncthreads();
    sh[t] += u;
    __syncthreads();
  }
  if (t < nb) bsum[t] = sh[t] - v;
}
__global__ __launch_bounds__(256) void k_scan3(int* __restrict__ rowptr, int* __restrict__ cursor,
                                               const int* __restrict__ bsum, int n) {
  int i = blockIdx.x * 256 + threadIdx.x;
  if (i < n) {
    int v = rowptr[i] + bsum[blockIdx.x];
    rowptr[i] = v;
    cursor[i] = v;
  }
  if (i == 0) rowptr[n] = Ecnt;
}
// scatter packed edge records: erec[pos] = (src, a0 | a1<<3 | a2<<6 | batch[src]<<9)
__global__ __launch_bounds__(256) void k_scatter(const int* __restrict__ ei, const int* __restrict__ ea,
                                                 const int* __restrict__ batch, int* __restrict__ cursor,
                                                 int2* __restrict__ erec) {
  int e = blockIdx.x * 256 + threadIdx.x;
  if (e < Ecnt) {
    int d = ei[Ecnt + e];
    int s = ei[e];
    int packed = ea[e * 3] | (ea[e * 3 + 1] << 3) | (ea[e * 3 + 2] << 6) | (batch[s] << 9);
    int pos = atomicAdd(&cursor[d], 1);
    erec[pos] = make_int2(s, packed);
  }
}

// ---- weight prep: conv W[k][n] fp32 -> fragment-packed bf16 hi/lo. ----
__global__ __launch_bounds__(256) void k_prep_w(const float* __restrict__ W, bf16* __restrict__ hi,
                                                bf16* __restrict__ lo, int nmats) {
  int c = blockIdx.x * 256 + threadIdx.x;
  if (c >= nmats * 8192) return;
  int lane = c & 63;
  int t = c >> 6;
  int kc8 = t & 7;
  int nt = (t >> 3) & 15;
  int m = t >> 7;
  int n = nt * 16 + (lane & 15);
  int k0 = kc8 * 32 + (lane >> 4) * 8;
  bf16x8 hv, lv;
#pragma unroll
  for (int j = 0; j < 8; ++j) {
    float w = W[(size_t)m * 65536 + (size_t)(k0 + j) * 256 + n];
    unsigned short h = f2bs(w);
    float res = w - bs2f(h);
    hv[j] = (short)h;
    lv[j] = (short)f2bs(res);
  }
  *(bf16x8*)&hi[(size_t)c * 8] = hv;
  *(bf16x8*)&lo[(size_t)c * 8] = lv;
}

// ---- encoders (1 wave per node, 4 ch/lane) ----
__global__ __launch_bounds__(256) void k_atom_encode(const int* __restrict__ x,
                                                     const float* __restrict__ aemb,
                                                     const float* __restrict__ vnw,
                                                     bf16* __restrict__ P) {
  int wave = threadIdx.x >> 6, lane = threadIdx.x & 63;
  int r = blockIdx.x * 4 + wave;
  if (r >= Ncnt) return;
  int c4 = lane * 4;
  const int* xr = x + (size_t)r * 9;
  float4 v = *(const float4*)&vnw[c4];
#pragma unroll
  for (int f = 0; f < 9; ++f) {
    float4 e = *(const float4*)&aemb[(size_t)((f << 6) + xr[f]) * Hc + c4];
    v.x += e.x; v.y += e.y; v.z += e.z; v.w += e.w;
  }
  *(ushort4*)&P[(size_t)r * Hc + c4] = f4tobf4(v);
}

__global__ __launch_bounds__(256) void k_init_vn(float* __restrict__ vn, float* __restrict__ vnt,
                                                 const float* __restrict__ vnw) {
  int idx = blockIdx.x * 256 + threadIdx.x;  // G*Hc total
  float v = vnw[idx & (Hc - 1)];
  vn[idx] = v;
  vnt[idx] = v;
}

// ---- segment-sum of relu(bn(P)) by sorted batch into vnt. 1 wave / 64 rows. ----
__global__ __launch_bounds__(256) void k_seg_vn(const bf16* __restrict__ P, const int* __restrict__ batch,
                                                float* __restrict__ vnt,
                                                const float* __restrict__ scb, const float* __restrict__ bbb) {
  int wave = threadIdx.x >> 6, lane = threadIdx.x & 63;
  int base = (blockIdx.x * 4 + wave) * 64;
  if (base >= Ncnt) return;
  int c4 = lane * 4;
  float4 scv = *(const float4*)&scb[c4];
  float4 bbv = *(const float4*)&bbb[c4];
  int end = imin(base + 64, Ncnt);
  float4 acc = make_float4(0.f, 0.f, 0.f, 0.f);
  int curg = batch[base];
  for (int r = base; r < end; ++r) {
    int g = batch[r];
    float4 v = bf4tof4(*(const ushort4*)&P[(size_t)r * Hc + c4]);
    v.x = fmaxf(fmaf(v.x, scv.x, bbv.x), 0.f); v.y = fmaxf(fmaf(v.y, scv.y, bbv.y), 0.f);
    v.z = fmaxf(fmaf(v.z, scv.z, bbv.z), 0.f); v.w = fmaxf(fmaf(v.w, scv.w, bbv.w), 0.f);
    if (g != curg) {
      float* d = &vnt[(size_t)curg * Hc + c4];
      atomicAdd(d, acc.x); atomicAdd(d + 1, acc.y); atomicAdd(d + 2, acc.z); atomicAdd(d + 3, acc.w);
      acc = make_float4(0.f, 0.f, 0.f, 0.f);
      curg = g;
    }
    acc.x += v.x; acc.y += v.y; acc.z += v.z; acc.w += v.w;
  }
  float* d = &vnt[(size_t)curg * Hc + c4];
  atomicAdd(d, acc.x); atomicAdd(d + 1, acc.y); atomicAdd(d + 2, acc.z); atomicAdd(d + 3, acc.w);
}

// ---- VN elementwise relu(bn(.)) fp32 -> vn AND vnt ----
__global__ __launch_bounds__(256) void k_vn_relu(const float* __restrict__ in, float* __restrict__ out,
                                                 float* __restrict__ out2,
                                                 const float* __restrict__ stats,
                                                 const float* __restrict__ gamma, const float* __restrict__ beta,
                                                 float invM) {
  int idx = blockIdx.x * 256 + threadIdx.x;
  int c = idx & (Hc - 1);
  float mu = stats[c] * invM;
  float var = stats[Hc + c] * invM - mu * mu;
  float sc = rsqrtf(var + BN_EPS) * gamma[c];
  float bb = beta[c] - mu * sc;
  float v = fmaxf(fmaf(in[idx], sc, bb), 0.f);
  out[idx] = v;
  out2[idx] = v;
}

// ---- final bn + global_add_pool (out pre-zeroed). 1 wave / 64 rows. ----
__global__ __launch_bounds__(256) void k_bn_pool(const bf16* __restrict__ P, const int* __restrict__ batch,
                                                 float* __restrict__ out,
                                                 const float* __restrict__ scb, const float* __restrict__ bbb) {
  int wave = threadIdx.x >> 6, lane = threadIdx.x & 63;
  int base = (blockIdx.x * 4 + wave) * 64;
  if (base >= Ncnt) return;
  int c4 = lane * 4;
  float4 scv = *(const float4*)&scb[c4];
  float4 bbv = *(const float4*)&bbb[c4];
  int end = imin(base + 64, Ncnt);
  float4 acc = make_float4(0.f, 0.f, 0.f, 0.f);
  int curg = batch[base];
  for (int r = base; r < end; ++r) {
    int g = batch[r];
    float4 v = bf4tof4(*(const ushort4*)&P[(size_t)r * Hc + c4]);
    v.x = fmaf(v.x, scv.x, bbv.x); v.y = fmaf(v.y, scv.y, bbv.y);
    v.z = fmaf(v.z, scv.z, bbv.z); v.w = fmaf(v.w, scv.w, bbv.w);
    if (g != curg) {
      float* d = &out[(size_t)curg * Hc + c4];
      atomicAdd(d, acc.x); atomicAdd(d + 1, acc.y); atomicAdd(d + 2, acc.z); atomicAdd(d + 3, acc.w);
      acc = make_float4(0.f, 0.f, 0.f, 0.f);
      curg = g;
    }
    acc.x += v.x; acc.y += v.y; acc.z += v.z; acc.w += v.w;
  }
  float* d = &out[(size_t)curg * Hc + c4];
  atomicAdd(d, acc.x); atomicAdd(d + 1, acc.y); atomicAdd(d + 2, acc.z); atomicAdd(d + 3, acc.w);
}

// ---- FUSED agg + MFMA GEMM: C[M,256] = agg(P) @ (Whi+Wlo) + bias (+R), fused BN-stats.
// Block = 64 dst rows. Phase 1: 8 half-waves aggregate 8 rows each (scattered P gathers,
// bond-emb, optional BN+VN) into the XOR-swizzled bf16 LDS A-tile (64x256).
// Phase 2: 4 waves (64x64 each, acc[4][4]) MFMA vs fragment-packed direct-global B.
// Epilogue: bf16 Cs tile -> coalesced R-add + u16x8 C store + fused stats.
__global__ __launch_bounds__(256, 3) void k_agg_gemm(const bf16* __restrict__ P,
                                                     const int* __restrict__ rowptr, const int2* __restrict__ erec,
                                                     const float* __restrict__ bemb,
                                                     const float* __restrict__ vn, const int* __restrict__ batch,
                                                     const float* __restrict__ scb, const float* __restrict__ bbb,
                                                     const bf16* __restrict__ Whi, const bf16* __restrict__ Wlo,
                                                     const float* __restrict__ bias,
                                                     const bf16* __restrict__ R, bf16* __restrict__ C,
                                                     float* __restrict__ stats, int M) {
  __shared__ __attribute__((aligned(16))) unsigned short As[64 * 256];
  __shared__ __attribute__((aligned(16))) unsigned short Cs[16 * 264];
  __shared__ float lsum[256], lsq[256];
  int tid = threadIdx.x;
  int wave = tid >> 6, lane = tid & 63;
  int quad = lane >> 4, l15 = lane & 15;
  int hw = tid >> 5, hl = tid & 31;
  int c8 = hl * 8;
  int row0 = blockIdx.x * 64;

  lsum[tid] = 0.f;
  lsq[tid] = 0.f;

  // ---- phase 1: aggregation into swizzled LDS ----
  bool hasbn = (scb != nullptr);
  float sc[8], bb[8];
  if (hasbn) {
    float4 s0 = *(const float4*)&scb[c8], s1 = *(const float4*)&scb[c8 + 4];
    float4 b0 = *(const float4*)&bbb[c8], b1 = *(const float4*)&bbb[c8 + 4];
    sc[0] = s0.x; sc[1] = s0.y; sc[2] = s0.z; sc[3] = s0.w;
    sc[4] = s1.x; sc[5] = s1.y; sc[6] = s1.z; sc[7] = s1.w;
    bb[0] = b0.x; bb[1] = b0.y; bb[2] = b0.z; bb[3] = b0.w;
    bb[4] = b1.x; bb[5] = b1.y; bb[6] = b1.z; bb[7] = b1.w;
  }
  int kci = c8 >> 6;
  int jg = (c8 >> 3) & 7;  // granule index within 64-col slice
  for (int q = 0; q < 8; ++q) {
    int rl = hw * 8 + q;
    int r = row0 + rl;
    float acc[8];
    if (r < M) {
      u16x8 pv = *(const u16x8*)&P[(size_t)r * Hc + c8];
      if (hasbn) {
        const float* vr = &vn[(size_t)batch[r] * Hc + c8];
        float4 w0 = *(const float4*)vr, w1 = *(const float4*)(vr + 4);
        float w[8] = {w0.x, w0.y, w0.z, w0.w, w1.x, w1.y, w1.z, w1.w};
#pragma unroll
        for (int k = 0; k < 8; ++k) acc[k] = fmaxf(fmaf(bs2f(pv[k]), sc[k], bb[k]), 0.f) + w[k];
      } else {
#pragma unroll
        for (int k = 0; k < 8; ++k) acc[k] = bs2f(pv[k]);
      }
      int j0 = rowptr[r], j1 = rowptr[r + 1];
      if (j0 < j1) {
        int2 er = erec[j0];
        for (int j = j0; j < j1; ++j) {
          int2 ern = (j + 1 < j1) ? erec[j + 1] : er;  // prefetch next record
          int s = er.x;
          int a0 = er.y & 7, a1 = (er.y >> 3) & 7, a2 = (er.y >> 6) & 7, g = er.y >> 9;
          u16x8 sv = *(const u16x8*)&P[(size_t)s * Hc + c8];
          const float* e0 = &bemb[(size_t)a0 * Hc + c8];
          const float* e1 = &bemb[(size_t)(8 + a1) * Hc + c8];
          const float* e2 = &bemb[(size_t)(16 + a2) * Hc + c8];
          float4 e0a = *(const float4*)e0, e0b = *(const float4*)(e0 + 4);
          float4 e1a = *(const float4*)e1, e1b = *(const float4*)(e1 + 4);
          float4 e2a = *(const float4*)e2, e2b = *(const float4*)(e2 + 4);
          float em[8] = {e0a.x + e1a.x + e2a.x, e0a.y + e1a.y + e2a.y,
                         e0a.z + e1a.z + e2a.z, e0a.w + e1a.w + e2a.w,
                         e0b.x + e1b.x + e2b.x, e0b.y + e1b.y + e2b.y,
                         e0b.z + e1b.z + e2b.z, e0b.w + e1b.w + e2b.w};
          if (hasbn) {
            const float* vr = &vn[(size_t)g * Hc + c8];
            float4 w0 = *(const float4*)vr, w1 = *(const float4*)(vr + 4);
            float w[8] = {w0.x, w0.y, w0.z, w0.w, w1.x, w1.y, w1.z, w1.w};
#pragma unroll
            for (int k = 0; k < 8; ++k) {
              float v = fmaxf(fmaf(bs2f(sv[k]), sc[k], bb[k]), 0.f) + w[k];
              acc[k] += fmaxf(v + em[k], 0.f) + MSG_EPS;
            }
          } else {
#pragma unroll
            for (int k = 0; k < 8; ++k)
              acc[k] += fmaxf(bs2f(sv[k]) + em[k], 0.f) + MSG_EPS;
          }
          er = ern;
        }
      }
    } else {
#pragma unroll
      for (int k = 0; k < 8; ++k) acc[k] = 0.f;
    }
    u16x8 ov;
#pragma unroll
    for (int k = 0; k < 8; ++k) ov[k] = f2bs(acc[k]);
    *(u16x8*)&As[rl * 256 + kci * 64 + ((jg ^ (rl & 7)) << 3)] = ov;
  }
  __syncthreads();

  // ---- phase 2: MFMA (wave = 64-col strip) ----
  int wc = wave * 64;
  f32x4 acc4[4][4];
#pragma unroll
  for (int i = 0; i < 4; ++i)
#pragma unroll
    for (int j = 0; j < 4; ++j) acc4[i][j] = (f32x4){0.f, 0.f, 0.f, 0.f};

#pragma unroll
  for (int kc8 = 0; kc8 < 8; ++kc8) {
    int kcs = kc8 >> 1;
    int g = (kc8 & 1) * 4 + quad;
    bf16x8 af[4];
#pragma unroll
    for (int mi = 0; mi < 4; ++mi) {
      int row = mi * 16 + l15;
      af[mi] = *(const bf16x8*)&As[row * 256 + kcs * 64 + ((g ^ (row & 7)) << 3)];
    }
#pragma unroll
    for (int nii = 0; nii < 4; ++nii) {
      int nt = wave * 4 + nii;
      size_t fo = (((size_t)nt * 8 + kc8) * 64 + lane) * 8;
      bf16x8 bh = *(const bf16x8*)&Whi[fo];
      bf16x8 bl = *(const bf16x8*)&Wlo[fo];
#pragma unroll
      for (int mi = 0; mi < 4; ++mi) {
        acc4[mi][nii] = __builtin_amdgcn_mfma_f32_16x16x32_bf16(af[mi], bh, acc4[mi][nii], 0, 0, 0);
        acc4[mi][nii] = __builtin_amdgcn_mfma_f32_16x16x32_bf16(af[mi], bl, acc4[mi][nii], 0, 0, 0);
      }
    }
  }

  // ---- epilogue: 4 passes; pass p handles 16-row group p ----
  float s8[8], q8[8];
#pragma unroll
  for (int k = 0; k < 8; ++k) { s8[k] = 0.f; q8[k] = 0.f; }

  for (int p = 0; p < 4; ++p) {
    int lr0 = quad * 4;
#pragma unroll
    for (int ni = 0; ni < 4; ++ni) {
      int col = wc + ni * 16 + l15;
      float bcol = bias[col];
#pragma unroll
      for (int j = 0; j < 4; ++j)
        Cs[(lr0 + j) * 264 + col] = f2bs(acc4[p][ni][j] + bcol);
    }
    __syncthreads();
#pragma unroll
    for (int i = 0; i < 2; ++i) {
      int slot = i * 256 + tid;
      int lr = slot >> 5;
      int grow = row0 + p * 16 + lr;
      if (grow < M) {
        u16x8 cv = *(const u16x8*)&Cs[lr * 264 + c8];
        float v[8];
#pragma unroll
        for (int k = 0; k < 8; ++k) v[k] = bs2f(cv[k]);
        if (R) {
          u16x8 rv = *(const u16x8*)&R[(size_t)grow * Hc + c8];
#pragma unroll
          for (int k = 0; k < 8; ++k) v[k] += bs2f(rv[k]);
        }
        u16x8 ov;
#pragma unroll
        for (int k = 0; k < 8; ++k) {
          ov[k] = f2bs(v[k]);
          s8[k] += v[k];
          q8[k] = fmaf(v[k], v[k], q8[k]);
        }
        *(u16x8*)&C[(size_t)grow * Hc + c8] = ov;
      }
    }
    __syncthreads();
  }

#pragma unroll
  for (int k = 0; k < 8; ++k) {
    atomicAdd(&lsum[c8 + k], s8[k]);
    atomicAdd(&lsq[c8 + k], q8[k]);
  }
  __syncthreads();
  atomicAdd(&stats[tid], lsum[tid]);
  atomicAdd(&stats[Hc + tid], lsq[tid]);
}

// ---- fp32 SIMT GEMM for VN MLP: C[M,256] = act(A) @ W + bias, fused stats. ----
__global__ __launch_bounds__(256) void k_gemm_f32(const float* __restrict__ A, const float* __restrict__ W,
                                                  const float* __restrict__ bias, float* __restrict__ C,
                                                  float* __restrict__ statsOut,
                                                  const float* __restrict__ statsIn,
                                                  const float* __restrict__ gIn, const float* __restrict__ bIn,
                                                  float invM, int M) {
  __shared__ float As[64][68];
  __shared__ float Ws[64][68];
  __shared__ float lsum[64], lsq[64];
  int tid = threadIdx.x;
  int row0 = blockIdx.x * 64;
  int col0 = blockIdx.y * 64;
  int tx = tid & 15, ty = tid >> 4;
  if (tid < 64) { lsum[tid] = 0.f; lsq[tid] = 0.f; }
  float acc[4][4] = {{0.f}};
  for (int k0 = 0; k0 < 256; k0 += 64) {
#pragma unroll
    for (int i = 0; i < 4; ++i) {
      int lin = tid + i * 256;
      int r = lin >> 4;
      int c4 = (lin & 15) << 2;
      int gr = row0 + r;
      float4 v = make_float4(0.f, 0.f, 0.f, 0.f);
      if (gr < M) v = *(const float4*)&A[(size_t)gr * Hc + k0 + c4];
      if (statsIn) {
        float4 sv = *(const float4*)&statsIn[k0 + c4];
        float4 qv = *(const float4*)&statsIn[Hc + k0 + c4];
        float4 gv = *(const float4*)&gIn[k0 + c4];
        float4 bv = *(const float4*)&bIn[k0 + c4];
        float mu, var, sc, bb;
        mu = sv.x * invM; var = qv.x * invM - mu * mu; sc = rsqrtf(var + BN_EPS) * gv.x; bb = bv.x - mu * sc;
        v.x = fmaxf(fmaf(v.x, sc, bb), 0.f);
        mu = sv.y * invM; var = qv.y * invM - mu * mu; sc = rsqrtf(var + BN_EPS) * gv.y; bb = bv.y - mu * sc;
        v.y = fmaxf(fmaf(v.y, sc, bb), 0.f);
        mu = sv.z * invM; var = qv.z * invM - mu * mu; sc = rsqrtf(var + BN_EPS) * gv.z; bb = bv.z - mu * sc;
        v.z = fmaxf(fmaf(v.z, sc, bb), 0.f);
        mu = sv.w * invM; var = qv.w * invM - mu * mu; sc = rsqrtf(var + BN_EPS) * gv.w; bb = bv.w - mu * sc;
        v.w = fmaxf(fmaf(v.w, sc, bb), 0.f);
      }
      As[r][c4] = v.x; As[r][c4 + 1] = v.y; As[r][c4 + 2] = v.z; As[r][c4 + 3] = v.w;
      float4 w = *(const float4*)&W[(size_t)(k0 + r) * Hc + col0 + c4];
      Ws[r][c4] = w.x; Ws[r][c4 + 1] = w.y; Ws[r][c4 + 2] = w.z; Ws[r][c4 + 3] = w.w;
    }
    __syncthreads();
#pragma unroll
    for (int k = 0; k < 64; ++k) {
      float a[4], w[4];
#pragma unroll
      for (int i = 0; i < 4; ++i) a[i] = As[ty * 4 + i][k];
#pragma unroll
      for (int j = 0; j < 4; ++j) w[j] = Ws[k][tx * 4 + j];
#pragma unroll
      for (int i = 0; i < 4; ++i)
#pragma unroll
        for (int j = 0; j < 4; ++j) acc[i][j] = fmaf(a[i], w[j], acc[i][j]);
    }
    __syncthreads();
  }
  float cs[4] = {0.f, 0.f, 0.f, 0.f}, cq[4] = {0.f, 0.f, 0.f, 0.f};
#pragma unroll
  for (int i = 0; i < 4; ++i) {
    int gr = row0 + ty * 4 + i;
    if (gr >= M) break;
#pragma unroll
    for (int j = 0; j < 4; ++j) {
      int gc = col0 + tx * 4 + j;
      float v = acc[i][j] + bias[gc];
      C[(size_t)gr * Hc + gc] = v;
      cs[j] += v;
      cq[j] = fmaf(v, v, cq[j]);
    }
  }
#pragma unroll
  for (int j = 0; j < 4; ++j) {
    atomicAdd(&lsum[tx * 4 + j], cs[j]);
    atomicAdd(&lsq[tx * 4 + j], cq[j]);
  }
  __syncthreads();
  if (tid < 64) {
    atomicAdd(&statsOut[col0 + tid], lsum[tid]);
    atomicAdd(&statsOut[Hc + col0 + tid], lsq[tid]);
  }
}

extern "C" void kernel_launch(void* const* d_in, const int* in_sizes, int n_in,
                              void* d_out, int out_size, void* d_ws, size_t ws_size,
                              hipStream_t stream) {
  const int* x = (const int*)d_in[0];
  const int* ei = (const int*)d_in[1];
  const int* ea = (const int*)d_in[2];
  const int* batch = (const int*)d_in[3];
  const float* aemb = (const float*)d_in[4];
  const float* bemb = (const float*)d_in[5];
  const float* vnw = (const float*)d_in[6];
  const float* conv_w = (const float*)d_in[7];
  const float* conv_b = (const float*)d_in[8];
  const float* ngamma = (const float*)d_in[9];
  const float* nbeta = (const float*)d_in[10];
  const float* vn_w = (const float*)d_in[11];
  const float* vn_b = (const float*)d_in[12];
  const float* vn_g = (const float*)d_in[13];
  const float* vn_be = (const float*)d_in[14];
  float* out = (float*)d_out;

  const size_t NODE = (size_t)Ncnt * Hc;
  const size_t GH = (size_t)Gcnt * Hc;
  const int nScanBlk = (Ncnt + 255) / 256;  // 586

  size_t off = 0;
  char* base = (char*)d_ws;
  auto take = [&](size_t bytes) { size_t o = off; off += (bytes + 15) & ~(size_t)15; return o; };
  float* vn = (float*)(base + take(GH * 4));
  float* vnt = (float*)(base + take(GH * 4));
  float* vnu = (float*)(base + take(GH * 4));
  float* vnv = (float*)(base + take(GH * 4));
  float* statsN = (float*)(base + take(2 * Hc * 4));
  float* statsV1 = (float*)(base + take(2 * Hc * 4));
  float* statsV2 = (float*)(base + take(2 * Hc * 4));
  float* scbN = (float*)(base + take(Hc * 4));
  float* bbbN = (float*)(base + take(Hc * 4));
  int* rowptr = (int*)(base + take((size_t)(Ncnt + 1) * 4));
  int* cursor = (int*)(base + take((size_t)Ncnt * 4));
  int2* erec = (int2*)(base + take((size_t)Ecnt * 8));
  int* bsum = (int*)(base + take((size_t)nScanBlk * 4));
  bf16* P0 = (bf16*)(base + take(NODE * 2));
  bf16* P1 = (bf16*)(base + take(NODE * 2));
  bf16* WhiC = (bf16*)(base + take((size_t)Lcnt * 65536 * 2));
  bf16* WloC = (bf16*)(base + take((size_t)Lcnt * 65536 * 2));
  const size_t NEED = off;
  if (ws_size < NEED) {
    k_zero<<<(int)((GH + 255) / 256), 256, 0, stream>>>(out, (int)GH);
    k_diag<<<1, 1, 0, stream>>>(out, 100000.f + (float)(ws_size / (1024.0 * 1024.0)));
    return;
  }

  const int eBlk = (Ecnt + 255) / 256;
  const int nWaveBlk = (Ncnt + 3) / 4;
  const int segBlk = (Ncnt + 255) / 256;
  const int ggN = (Ncnt + 63) / 64;        // 2344 fused blocks
  const dim3 gv(Gcnt / 64, 4);
  const float invN = 1.f / Ncnt;
  const float invG = 1.f / Gcnt;

  // CSR build (parallel scan) + packed edge records
  k_zero_int<<<nScanBlk, 256, 0, stream>>>(cursor, Ncnt);
  k_count<<<eBlk, 256, 0, stream>>>(ei, cursor);
  k_scan1<<<nScanBlk, 256, 0, stream>>>(cursor, rowptr, bsum, Ncnt);
  k_scan2<<<1, 1024, 0, stream>>>(bsum, nScanBlk);
  k_scan3<<<nScanBlk, 256, 0, stream>>>(rowptr, cursor, bsum, Ncnt);
  k_scatter<<<eBlk, 256, 0, stream>>>(ei, ea, batch, cursor, erec);

  // conv weight prep (hi/lo, fragment-packed)
  k_prep_w<<<(Lcnt * 8192 + 255) / 256, 256, 0, stream>>>(conv_w, WhiC, WloC, Lcnt);

  // Encoders + fused agg+conv0 (stats fused for layer-1 BN)
  k_atom_encode<<<nWaveBlk, 256, 0, stream>>>(x, aemb, vnw, P0);
  k_init_vn<<<(int)(GH / 256), 256, 0, stream>>>(vn, vnt, vnw);
  k_zero<<<2, 256, 0, stream>>>(statsN, 2 * Hc);
  bf16* pa = P0;  // current h (gather source)
  bf16* pb = P1;  // output
  k_agg_gemm<<<ggN, 256, 0, stream>>>(pa, rowptr, erec, bemb,
                                      nullptr, nullptr, nullptr, nullptr,
                                      WhiC, WloC, conv_b, nullptr, pb, statsN, Ncnt);
  { bf16* t = pa; pa = pb; pb = t; }

  for (int l = 1; l < Lcnt; ++l) {
    int p = l - 1;
    // BN constants for this layer's node BN (also zeroes statsN for next GEMM)
    k_bnprep<<<1, 256, 0, stream>>>(statsN, ngamma + (size_t)p * Hc, nbeta + (size_t)p * Hc,
                                    scbN, bbbN, invN);
    // vnt already = vn (dual-store); add segsum(relu(bn(pa)))
    k_seg_vn<<<segBlk, 256, 0, stream>>>(pa, batch, vnt, scbN, bbbN);
    // zero both VN stats buffers (adjacent) in one launch
    k_zero<<<4, 256, 0, stream>>>(statsV1, 4 * Hc);
    // VN MLP j=0: vnu = vnt @ w0 + b0 (stats -> V1)
    k_gemm_f32<<<gv, 256, 0, stream>>>(vnt, vn_w + (size_t)(2 * p) * 65536,
                                       vn_b + (size_t)(2 * p) * Hc, vnu, statsV1,
                                       nullptr, nullptr, nullptr, invG, Gcnt);
    // VN MLP j=1: vnv = relu(bnV1(vnu)) @ w1 + b1 (stats -> V2)
    k_gemm_f32<<<gv, 256, 0, stream>>>(vnu, vn_w + (size_t)(2 * p + 1) * 65536,
                                       vn_b + (size_t)(2 * p + 1) * Hc, vnv, statsV2,
                                       statsV1, vn_g + (size_t)(2 * p) * Hc,
                                       vn_be + (size_t)(2 * p) * Hc, invG, Gcnt);
    // vn = relu(bnV2(vnv)); also seeds vnt for next layer
    k_vn_relu<<<(int)(GH / 256), 256, 0, stream>>>(vnv, vn, vnt, statsV2,
                                                   vn_g + (size_t)(2 * p + 1) * Hc,
                                                   vn_be + (size_t)(2 * p + 1) * Hc, invG);
    // fused: pb = agg(h2(pa)) @ W + bias + pa   (h2 = relu(bn(pa)) + vn[batch])
    k_agg_gemm<<<ggN, 256, 0, stream>>>(pa, rowptr, erec, bemb,
                                        vn, batch, scbN, bbbN,
                                        WhiC + (size_t)l * 65536, WloC + (size_t)l * 65536,
                                        conv_b + (size_t)l * Hc, pa, pb, statsN, Ncnt);
    { bf16* t = pa; pa = pb; pb = t; }
  }

  // Final BN + global add pool
  k_bnprep<<<1, 256, 0, stream>>>(statsN, ngamma + (size_t)(Lcnt - 1) * Hc,
                                  nbeta + (size_t)(Lcnt - 1) * Hc, scbN, bbbN, invN);
  k_zero<<<(int)((GH + 255) / 256), 256, 0, stream>>>(out, (int)GH);
  k_bn_pool<<<segBlk, 256, 0, stream>>>(pa, batch, out, scbN, bbbN);
}

// Round 15
// 2274.316 us; speedup vs baseline: 1.0382x; 1.0382x over previous
//
#include <hip/hip_runtime.h>
#include <hip/hip_bf16.h>

// DeeperGCN on MI355X — round 15: R13 structure (separate agg/gemm) with the GEMM's
// A-tile staged full-K in ONE shot (8 gll16/thread, 1 barrier/block instead of 4) —
// frees the K loop to software-pipeline B loads + MFMA without vmcnt(0) drains.
// N=150000, E=300000, G=4096, H=256, L=7.

#define Ncnt 150000
#define Ecnt 300000
#define Gcnt 4096
#define Hc 256
#define Lcnt 7
#define BN_EPS 1e-5f
#define MSG_EPS 1e-7f

typedef __hip_bfloat16 bf16;
typedef __attribute__((ext_vector_type(8))) short bf16x8;
typedef __attribute__((ext_vector_type(8))) unsigned short u16x8;
typedef __attribute__((ext_vector_type(4))) float f32x4;

static __device__ __forceinline__ int imin(int a, int b) { return a < b ? a : b; }

static __device__ __forceinline__ float bs2f(unsigned short s) {
  unsigned u = ((unsigned)s) << 16;
  union { unsigned u; float f; } c; c.u = u; return c.f;
}
static __device__ __forceinline__ unsigned short f2bs(float f) {
  bf16 h = __float2bfloat16(f);
  union { bf16 h; unsigned short s; } c; c.h = h; return c.s;
}
static __device__ __forceinline__ float4 bf4tof4(ushort4 u) {
  float4 r; r.x = bs2f(u.x); r.y = bs2f(u.y); r.z = bs2f(u.z); r.w = bs2f(u.w); return r;
}
static __device__ __forceinline__ ushort4 f4tobf4(float4 v) {
  ushort4 u; u.x = f2bs(v.x); u.y = f2bs(v.y); u.z = f2bs(v.z); u.w = f2bs(v.w); return u;
}

// async global->LDS, 16B per lane; lds dst must be the wave-uniform chunk base.
static __device__ __forceinline__ void gll16(const bf16* g, const short* l) {
  __builtin_amdgcn_global_load_lds((const __attribute__((address_space(1))) void*)g,
                                   (__attribute__((address_space(3))) void*)l, 16, 0, 0);
}

__global__ __launch_bounds__(256) void k_zero(float* __restrict__ p, int n) {
  int i = blockIdx.x * 256 + threadIdx.x;
  if (i < n) p[i] = 0.f;
}
__global__ __launch_bounds__(256) void k_zero_int(int* __restrict__ p, int n) {
  int i = blockIdx.x * 256 + threadIdx.x;
  if (i < n) p[i] = 0;
}
__global__ void k_diag(float* __restrict__ out, float v) { out[0] = v; }

// ---- BN scale/bias precompute + stats recycle ----
__global__ __launch_bounds__(256) void k_bnprep(float* __restrict__ stats,
                                                const float* __restrict__ gamma, const float* __restrict__ beta,
                                                float* __restrict__ scb, float* __restrict__ bbb, float invM) {
  int c = threadIdx.x;
  float mu = stats[c] * invM;
  float var = stats[Hc + c] * invM - mu * mu;
  float sc = rsqrtf(var + BN_EPS) * gamma[c];
  scb[c] = sc;
  bbb[c] = beta[c] - mu * sc;
  stats[c] = 0.f;
  stats[Hc + c] = 0.f;
}

// ---- CSR build (counting sort by dst) ----
__global__ __launch_bounds__(256) void k_count(const int* __restrict__ ei, int* __restrict__ cnt) {
  int e = blockIdx.x * 256 + threadIdx.x;
  if (e < Ecnt) atomicAdd(&cnt[ei[Ecnt + e]], 1);
}
__global__ __launch_bounds__(256) void k_scan1(const int* __restrict__ cnt, int* __restrict__ rowptr,
                                               int* __restrict__ bsum, int n) {
  __shared__ int sh[256];
  int t = threadIdx.x;
  int i = blockIdx.x * 256 + t;
  int v = (i < n) ? cnt[i] : 0;
  sh[t] = v;
  __syncthreads();
#pragma unroll
  for (int off = 1; off < 256; off <<= 1) {
    int u = (t >= off) ? sh[t - off] : 0;
    __syncthreads();
    sh[t] += u;
    __syncthreads();
  }
  if (i < n) rowptr[i] = sh[t] - v;
  if (t == 255) bsum[blockIdx.x] = sh[255];
}
__global__ __launch_bounds__(1024) void k_scan2(int* __restrict__ bsum, int nb) {
  __shared__ int sh[1024];
  int t = threadIdx.x;
  int v = (t < nb) ? bsum[t] : 0;
  sh[t] = v;
  __syncthreads();
#pragma unroll
  for (int off = 1; off < 1024; off <<= 1) {
    int u = (t >= off) ? sh[t - off] : 0;
    __syncthreads();
    sh[t] += u;
    __syncthreads();
  }
  if (t < nb) bsum[t] = sh[t] - v;
}
__global__ __launch_bounds__(256) void k_scan3(int* __restrict__ rowptr, int* __restrict__ cursor,
                                               const int* __restrict__ bsum, int n) {
  int i = blockIdx.x * 256 + threadIdx.x;
  if (i < n) {
    int v = rowptr[i] + bsum[blockIdx.x];
    rowptr[i] = v;
    cursor[i] = v;
  }
  if (i == 0) rowptr[n] = Ecnt;
}
// scatter packed edge records: erec[pos] = (src, a0 | a1<<3 | a2<<6 | batch[src]<<9)
__global__ __launch_bounds__(256) void k_scatter(const int* __restrict__ ei, const int* __restrict__ ea,
                                                 const int* __restrict__ batch, int* __restrict__ cursor,
                                                 int2* __restrict__ erec) {
  int e = blockIdx.x * 256 + threadIdx.x;
  if (e < Ecnt) {
    int d = ei[Ecnt + e];
    int s = ei[e];
    int packed = ea[e * 3] | (ea[e * 3 + 1] << 3) | (ea[e * 3 + 2] << 6) | (batch[s] << 9);
    int pos = atomicAdd(&cursor[d], 1);
    erec[pos] = make_int2(s, packed);
  }
}

// ---- weight prep: conv W[k][n] fp32 -> fragment-packed bf16 hi/lo. ----
__global__ __launch_bounds__(256) void k_prep_w(const float* __restrict__ W, bf16* __restrict__ hi,
                                                bf16* __restrict__ lo, int nmats) {
  int c = blockIdx.x * 256 + threadIdx.x;
  if (c >= nmats * 8192) return;
  int lane = c & 63;
  int t = c >> 6;
  int kc8 = t & 7;
  int nt = (t >> 3) & 15;
  int m = t >> 7;
  int n = nt * 16 + (lane & 15);
  int k0 = kc8 * 32 + (lane >> 4) * 8;
  bf16x8 hv, lv;
#pragma unroll
  for (int j = 0; j < 8; ++j) {
    float w = W[(size_t)m * 65536 + (size_t)(k0 + j) * 256 + n];
    unsigned short h = f2bs(w);
    float res = w - bs2f(h);
    hv[j] = (short)h;
    lv[j] = (short)f2bs(res);
  }
  *(bf16x8*)&hi[(size_t)c * 8] = hv;
  *(bf16x8*)&lo[(size_t)c * 8] = lv;
}

// ---- encoders (1 wave per node, 4 ch/lane) ----
__global__ __launch_bounds__(256) void k_atom_encode(const int* __restrict__ x,
                                                     const float* __restrict__ aemb,
                                                     const float* __restrict__ vnw,
                                                     bf16* __restrict__ P) {
  int wave = threadIdx.x >> 6, lane = threadIdx.x & 63;
  int r = blockIdx.x * 4 + wave;
  if (r >= Ncnt) return;
  int c4 = lane * 4;
  const int* xr = x + (size_t)r * 9;
  float4 v = *(const float4*)&vnw[c4];
#pragma unroll
  for (int f = 0; f < 9; ++f) {
    float4 e = *(const float4*)&aemb[(size_t)((f << 6) + xr[f]) * Hc + c4];
    v.x += e.x; v.y += e.y; v.z += e.z; v.w += e.w;
  }
  *(ushort4*)&P[(size_t)r * Hc + c4] = f4tobf4(v);
}

__global__ __launch_bounds__(256) void k_init_vn(float* __restrict__ vn, float* __restrict__ vnt,
                                                 const float* __restrict__ vnw) {
  int idx = blockIdx.x * 256 + threadIdx.x;  // G*Hc total
  float v = vnw[idx & (Hc - 1)];
  vn[idx] = v;
  vnt[idx] = v;
}

// ---- aggregation: half-wave (32 lanes) per node, 8 ch/lane ----
__global__ __launch_bounds__(256) void k_agg(const bf16* __restrict__ P, bf16* __restrict__ T,
                                             const int* __restrict__ rowptr, const int2* __restrict__ erec,
                                             const float* __restrict__ bemb,
                                             const float* __restrict__ vn, const int* __restrict__ batch,
                                             const float* __restrict__ scb, const float* __restrict__ bbb) {
  int hw = threadIdx.x >> 5, lane = threadIdx.x & 31;
  int r = blockIdx.x * 8 + hw;
  if (r >= Ncnt) return;
  int c8 = lane * 8;
  bool hasbn = (scb != nullptr);
  float sc[8], bb[8];
  if (hasbn) {
    float4 s0 = *(const float4*)&scb[c8], s1 = *(const float4*)&scb[c8 + 4];
    float4 b0 = *(const float4*)&bbb[c8], b1 = *(const float4*)&bbb[c8 + 4];
    sc[0] = s0.x; sc[1] = s0.y; sc[2] = s0.z; sc[3] = s0.w;
    sc[4] = s1.x; sc[5] = s1.y; sc[6] = s1.z; sc[7] = s1.w;
    bb[0] = b0.x; bb[1] = b0.y; bb[2] = b0.z; bb[3] = b0.w;
    bb[4] = b1.x; bb[5] = b1.y; bb[6] = b1.z; bb[7] = b1.w;
  }
  float acc[8];
  {
    u16x8 pv = *(const u16x8*)&P[(size_t)r * Hc + c8];
    if (hasbn) {
      const float* vr = &vn[(size_t)batch[r] * Hc + c8];
      float4 w0 = *(const float4*)vr, w1 = *(const float4*)(vr + 4);
      float w[8] = {w0.x, w0.y, w0.z, w0.w, w1.x, w1.y, w1.z, w1.w};
#pragma unroll
      for (int k = 0; k < 8; ++k) acc[k] = fmaxf(fmaf(bs2f(pv[k]), sc[k], bb[k]), 0.f) + w[k];
    } else {
#pragma unroll
      for (int k = 0; k < 8; ++k) acc[k] = bs2f(pv[k]);
    }
  }
  int j0 = rowptr[r], j1 = rowptr[r + 1];
  if (j0 < j1) {
    int2 er = erec[j0];
    for (int j = j0; j < j1; ++j) {
      int2 ern = (j + 1 < j1) ? erec[j + 1] : er;  // prefetch next record
      int s = er.x;
      int a0 = er.y & 7, a1 = (er.y >> 3) & 7, a2 = (er.y >> 6) & 7, g = er.y >> 9;
      u16x8 sv = *(const u16x8*)&P[(size_t)s * Hc + c8];
      const float* e0 = &bemb[(size_t)a0 * Hc + c8];
      const float* e1 = &bemb[(size_t)(8 + a1) * Hc + c8];
      const float* e2 = &bemb[(size_t)(16 + a2) * Hc + c8];
      float4 e0a = *(const float4*)e0, e0b = *(const float4*)(e0 + 4);
      float4 e1a = *(const float4*)e1, e1b = *(const float4*)(e1 + 4);
      float4 e2a = *(const float4*)e2, e2b = *(const float4*)(e2 + 4);
      float em[8] = {e0a.x + e1a.x + e2a.x, e0a.y + e1a.y + e2a.y,
                     e0a.z + e1a.z + e2a.z, e0a.w + e1a.w + e2a.w,
                     e0b.x + e1b.x + e2b.x, e0b.y + e1b.y + e2b.y,
                     e0b.z + e1b.z + e2b.z, e0b.w + e1b.w + e2b.w};
      if (hasbn) {
        const float* vr = &vn[(size_t)g * Hc + c8];
        float4 w0 = *(const float4*)vr, w1 = *(const float4*)(vr + 4);
        float w[8] = {w0.x, w0.y, w0.z, w0.w, w1.x, w1.y, w1.z, w1.w};
#pragma unroll
        for (int k = 0; k < 8; ++k) {
          float v = fmaxf(fmaf(bs2f(sv[k]), sc[k], bb[k]), 0.f) + w[k];
          acc[k] += fmaxf(v + em[k], 0.f) + MSG_EPS;
        }
      } else {
#pragma unroll
        for (int k = 0; k < 8; ++k)
          acc[k] += fmaxf(bs2f(sv[k]) + em[k], 0.f) + MSG_EPS;
      }
      er = ern;
    }
  }
  u16x8 ov;
#pragma unroll
  for (int k = 0; k < 8; ++k) ov[k] = f2bs(acc[k]);
  *(u16x8*)&T[(size_t)r * Hc + c8] = ov;
}

// ---- segment-sum of relu(bn(P)) by sorted batch into vnt. 1 wave / 64 rows. ----
__global__ __launch_bounds__(256) void k_seg_vn(const bf16* __restrict__ P, const int* __restrict__ batch,
                                                float* __restrict__ vnt,
                                                const float* __restrict__ scb, const float* __restrict__ bbb) {
  int wave = threadIdx.x >> 6, lane = threadIdx.x & 63;
  int base = (blockIdx.x * 4 + wave) * 64;
  if (base >= Ncnt) return;
  int c4 = lane * 4;
  float4 scv = *(const float4*)&scb[c4];
  float4 bbv = *(const float4*)&bbb[c4];
  int end = imin(base + 64, Ncnt);
  float4 acc = make_float4(0.f, 0.f, 0.f, 0.f);
  int curg = batch[base];
  for (int r = base; r < end; ++r) {
    int g = batch[r];
    float4 v = bf4tof4(*(const ushort4*)&P[(size_t)r * Hc + c4]);
    v.x = fmaxf(fmaf(v.x, scv.x, bbv.x), 0.f); v.y = fmaxf(fmaf(v.y, scv.y, bbv.y), 0.f);
    v.z = fmaxf(fmaf(v.z, scv.z, bbv.z), 0.f); v.w = fmaxf(fmaf(v.w, scv.w, bbv.w), 0.f);
    if (g != curg) {
      float* d = &vnt[(size_t)curg * Hc + c4];
      atomicAdd(d, acc.x); atomicAdd(d + 1, acc.y); atomicAdd(d + 2, acc.z); atomicAdd(d + 3, acc.w);
      acc = make_float4(0.f, 0.f, 0.f, 0.f);
      curg = g;
    }
    acc.x += v.x; acc.y += v.y; acc.z += v.z; acc.w += v.w;
  }
  float* d = &vnt[(size_t)curg * Hc + c4];
  atomicAdd(d, acc.x); atomicAdd(d + 1, acc.y); atomicAdd(d + 2, acc.z); atomicAdd(d + 3, acc.w);
}

// ---- VN elementwise relu(bn(.)) fp32 -> vn AND vnt ----
__global__ __launch_bounds__(256) void k_vn_relu(const float* __restrict__ in, float* __restrict__ out,
                                                 float* __restrict__ out2,
                                                 const float* __restrict__ stats,
                                                 const float* __restrict__ gamma, const float* __restrict__ beta,
                                                 float invM) {
  int idx = blockIdx.x * 256 + threadIdx.x;
  int c = idx & (Hc - 1);
  float mu = stats[c] * invM;
  float var = stats[Hc + c] * invM - mu * mu;
  float sc = rsqrtf(var + BN_EPS) * gamma[c];
  float bb = beta[c] - mu * sc;
  float v = fmaxf(fmaf(in[idx], sc, bb), 0.f);
  out[idx] = v;
  out2[idx] = v;
}

// ---- final bn + global_add_pool (out pre-zeroed). 1 wave / 64 rows. ----
__global__ __launch_bounds__(256) void k_bn_pool(const bf16* __restrict__ P, const int* __restrict__ batch,
                                                 float* __restrict__ out,
                                                 const float* __restrict__ scb, const float* __restrict__ bbb) {
  int wave = threadIdx.x >> 6, lane = threadIdx.x & 63;
  int base = (blockIdx.x * 4 + wave) * 64;
  if (base >= Ncnt) return;
  int c4 = lane * 4;
  float4 scv = *(const float4*)&scb[c4];
  float4 bbv = *(const float4*)&bbb[c4];
  int end = imin(base + 64, Ncnt);
  float4 acc = make_float4(0.f, 0.f, 0.f, 0.f);
  int curg = batch[base];
  for (int r = base; r < end; ++r) {
    int g = batch[r];
    float4 v = bf4tof4(*(const ushort4*)&P[(size_t)r * Hc + c4]);
    v.x = fmaf(v.x, scv.x, bbv.x); v.y = fmaf(v.y, scv.y, bbv.y);
    v.z = fmaf(v.z, scv.z, bbv.z); v.w = fmaf(v.w, scv.w, bbv.w);
    if (g != curg) {
      float* d = &out[(size_t)curg * Hc + c4];
      atomicAdd(d, acc.x); atomicAdd(d + 1, acc.y); atomicAdd(d + 2, acc.z); atomicAdd(d + 3, acc.w);
      acc = make_float4(0.f, 0.f, 0.f, 0.f);
      curg = g;
    }
    acc.x += v.x; acc.y += v.y; acc.z += v.z; acc.w += v.w;
  }
  float* d = &out[(size_t)curg * Hc + c4];
  atomicAdd(d, acc.x); atomicAdd(d + 1, acc.y); atomicAdd(d + 2, acc.z); atomicAdd(d + 3, acc.w);
}

// ---- MFMA node GEMM: C[M,256] = A @ (Whi+Wlo) + bias (+R), fused BN-stats.
// Block 64 rows x 256 cols, 4 waves side-by-side in N (64x64 each, acc[4][4]=64 AGPR).
// A: FULL K=256 staged in one shot (8 gll16/thread, swizzle on global addr) -> ONE
// barrier per block; K loop then runs barrier-free (B direct-global, pipelined).
// Epilogue: bf16 Cs tile -> coalesced R-add + u16x8 C store + fused stats.
__global__ __launch_bounds__(256, 3) void k_gemm_mfma(const bf16* __restrict__ A, const bf16* __restrict__ Whi,
                                                      const bf16* __restrict__ Wlo, const float* __restrict__ bias,
                                                      const bf16* __restrict__ R, bf16* __restrict__ C,
                                                      float* __restrict__ stats, int M) {
  __shared__ __attribute__((aligned(16))) short As[64 * 256];
  __shared__ __attribute__((aligned(16))) unsigned short Cs[16 * 264];
  __shared__ float lsum[256], lsq[256];
  int tid = threadIdx.x;
  int wave = tid >> 6, lane = tid & 63;
  int quad = lane >> 4, l15 = lane & 15;
  int wc = wave * 64;             // wave's 64-col strip
  int row0 = blockIdx.x * 64;

  lsum[tid] = 0.f;
  lsq[tid] = 0.f;

  // stage full 64x256 A tile: slot s holds global granule ((s&7)^(r&7)) of slice (s>>3)&3
#pragma unroll
  for (int i = 0; i < 8; ++i) {
    int s = i * 256 + tid;
    int r = s >> 5;             // row 0..63 (32 granules per row)
    int j = s & 31;
    int slice = j >> 3;         // 64-col slice 0..3
    int jg = (j & 7) ^ (r & 7); // swizzled granule within slice
    int ar = row0 + r; if (ar >= M) ar = M - 1;  // clamp: garbage rows never stored
    gll16(A + (size_t)ar * Hc + slice * 64 + jg * 8, &As[s * 8]);
  }
  __syncthreads();

  f32x4 acc[4][4];
#pragma unroll
  for (int i = 0; i < 4; ++i)
#pragma unroll
    for (int j = 0; j < 4; ++j) acc[i][j] = (f32x4){0.f, 0.f, 0.f, 0.f};

#pragma unroll
  for (int kc8 = 0; kc8 < 8; ++kc8) {
    int kcs = kc8 >> 1;
    int g = (kc8 & 1) * 4 + quad;
    bf16x8 af[4];
#pragma unroll
    for (int mi = 0; mi < 4; ++mi) {
      int row = mi * 16 + l15;
      af[mi] = *(const bf16x8*)&As[row * 256 + kcs * 64 + ((g ^ (row & 7)) << 3)];
    }
#pragma unroll
    for (int nii = 0; nii < 4; ++nii) {
      int nt = wave * 4 + nii;
      size_t fo = (((size_t)nt * 8 + kc8) * 64 + lane) * 8;
      bf16x8 bh = *(const bf16x8*)&Whi[fo];
      bf16x8 bl = *(const bf16x8*)&Wlo[fo];
#pragma unroll
      for (int mi = 0; mi < 4; ++mi) {
        acc[mi][nii] = __builtin_amdgcn_mfma_f32_16x16x32_bf16(af[mi], bh, acc[mi][nii], 0, 0, 0);
        acc[mi][nii] = __builtin_amdgcn_mfma_f32_16x16x32_bf16(af[mi], bl, acc[mi][nii], 0, 0, 0);
      }
    }
  }

  // ---- epilogue: 4 passes; pass p handles 16-row group p ----
  float s8[8], q8[8];
#pragma unroll
  for (int k = 0; k < 8; ++k) { s8[k] = 0.f; q8[k] = 0.f; }
  int cg8 = (tid & 31) * 8;  // thread's fixed 8-col group within 256

  for (int p = 0; p < 4; ++p) {
    int lr0 = quad * 4;
#pragma unroll
    for (int ni = 0; ni < 4; ++ni) {
      int col = wc + ni * 16 + l15;          // 0..255
      float bcol = bias[col];
#pragma unroll
      for (int j = 0; j < 4; ++j)
        Cs[(lr0 + j) * 264 + col] = f2bs(acc[p][ni][j] + bcol);
    }
    __syncthreads();
#pragma unroll
    for (int i = 0; i < 2; ++i) {
      int slot = i * 256 + tid;
      int lr = slot >> 5;                    // 0..15
      int grow = row0 + p * 16 + lr;
      if (grow < M) {
        u16x8 cv = *(const u16x8*)&Cs[lr * 264 + cg8];
        float v[8];
#pragma unroll
        for (int k = 0; k < 8; ++k) v[k] = bs2f(cv[k]);
        if (R) {
          u16x8 rv = *(const u16x8*)&R[(size_t)grow * Hc + cg8];
#pragma unroll
          for (int k = 0; k < 8; ++k) v[k] += bs2f(rv[k]);
        }
        u16x8 ov;
#pragma unroll
        for (int k = 0; k < 8; ++k) {
          ov[k] = f2bs(v[k]);
          s8[k] += v[k];
          q8[k] = fmaf(v[k], v[k], q8[k]);
        }
        *(u16x8*)&C[(size_t)grow * Hc + cg8] = ov;
      }
    }
    __syncthreads();
  }

#pragma unroll
  for (int k = 0; k < 8; ++k) {
    atomicAdd(&lsum[cg8 + k], s8[k]);
    atomicAdd(&lsq[cg8 + k], q8[k]);
  }
  __syncthreads();
  atomicAdd(&stats[tid], lsum[tid]);
  atomicAdd(&stats[Hc + tid], lsq[tid]);
}

// ---- fp32 SIMT GEMM for VN MLP: C[M,256] = act(A) @ W + bias, fused stats. ----
__global__ __launch_bounds__(256) void k_gemm_f32(const float* __restrict__ A, const float* __restrict__ W,
                                                  const float* __restrict__ bias, float* __restrict__ C,
                                                  float* __restrict__ statsOut,
                                                  const float* __restrict__ statsIn,
                                                  const float* __restrict__ gIn, const float* __restrict__ bIn,
                                                  float invM, int M) {
  __shared__ float As[64][68];
  __shared__ float Ws[64][68];
  __shared__ float lsum[64], lsq[64];
  int tid = threadIdx.x;
  int row0 = blockIdx.x * 64;
  int col0 = blockIdx.y * 64;
  int tx = tid & 15, ty = tid >> 4;
  if (tid < 64) { lsum[tid] = 0.f; lsq[tid] = 0.f; }
  float acc[4][4] = {{0.f}};
  for (int k0 = 0; k0 < 256; k0 += 64) {
#pragma unroll
    for (int i = 0; i < 4; ++i) {
      int lin = tid + i * 256;
      int r = lin >> 4;
      int c4 = (lin & 15) << 2;
      int gr = row0 + r;
      float4 v = make_float4(0.f, 0.f, 0.f, 0.f);
      if (gr < M) v = *(const float4*)&A[(size_t)gr * Hc + k0 + c4];
      if (statsIn) {
        float4 sv = *(const float4*)&statsIn[k0 + c4];
        float4 qv = *(const float4*)&statsIn[Hc + k0 + c4];
        float4 gv = *(const float4*)&gIn[k0 + c4];
        float4 bv = *(const float4*)&bIn[k0 + c4];
        float mu, var, sc, bb;
        mu = sv.x * invM; var = qv.x * invM - mu * mu; sc = rsqrtf(var + BN_EPS) * gv.x; bb = bv.x - mu * sc;
        v.x = fmaxf(fmaf(v.x, sc, bb), 0.f);
        mu = sv.y * invM; var = qv.y * invM - mu * mu; sc = rsqrtf(var + BN_EPS) * gv.y; bb = bv.y - mu * sc;
        v.y = fmaxf(fmaf(v.y, sc, bb), 0.f);
        mu = sv.z * invM; var = qv.z * invM - mu * mu; sc = rsqrtf(var + BN_EPS) * gv.z; bb = bv.z - mu * sc;
        v.z = fmaxf(fmaf(v.z, sc, bb), 0.f);
        mu = sv.w * invM; var = qv.w * invM - mu * mu; sc = rsqrtf(var + BN_EPS) * gv.w; bb = bv.w - mu * sc;
        v.w = fmaxf(fmaf(v.w, sc, bb), 0.f);
      }
      As[r][c4] = v.x; As[r][c4 + 1] = v.y; As[r][c4 + 2] = v.z; As[r][c4 + 3] = v.w;
      float4 w = *(const float4*)&W[(size_t)(k0 + r) * Hc + col0 + c4];
      Ws[r][c4] = w.x; Ws[r][c4 + 1] = w.y; Ws[r][c4 + 2] = w.z; Ws[r][c4 + 3] = w.w;
    }
    __syncthreads();
#pragma unroll
    for (int k = 0; k < 64; ++k) {
      float a[4], w[4];
#pragma unroll
      for (int i = 0; i < 4; ++i) a[i] = As[ty * 4 + i][k];
#pragma unroll
      for (int j = 0; j < 4; ++j) w[j] = Ws[k][tx * 4 + j];
#pragma unroll
      for (int i = 0; i < 4; ++i)
#pragma unroll
        for (int j = 0; j < 4; ++j) acc[i][j] = fmaf(a[i], w[j], acc[i][j]);
    }
    __syncthreads();
  }
  float cs[4] = {0.f, 0.f, 0.f, 0.f}, cq[4] = {0.f, 0.f, 0.f, 0.f};
#pragma unroll
  for (int i = 0; i < 4; ++i) {
    int gr = row0 + ty * 4 + i;
    if (gr >= M) break;
#pragma unroll
    for (int j = 0; j < 4; ++j) {
      int gc = col0 + tx * 4 + j;
      float v = acc[i][j] + bias[gc];
      C[(size_t)gr * Hc + gc] = v;
      cs[j] += v;
      cq[j] = fmaf(v, v, cq[j]);
    }
  }
#pragma unroll
  for (int j = 0; j < 4; ++j) {
    atomicAdd(&lsum[tx * 4 + j], cs[j]);
    atomicAdd(&lsq[tx * 4 + j], cq[j]);
  }
  __syncthreads();
  if (tid < 64) {
    atomicAdd(&statsOut[col0 + tid], lsum[tid]);
    atomicAdd(&statsOut[Hc + col0 + tid], lsq[tid]);
  }
}

extern "C" void kernel_launch(void* const* d_in, const int* in_sizes, int n_in,
                              void* d_out, int out_size, void* d_ws, size_t ws_size,
                              hipStream_t stream) {
  const int* x = (const int*)d_in[0];
  const int* ei = (const int*)d_in[1];
  const int* ea = (const int*)d_in[2];
  const int* batch = (const int*)d_in[3];
  const float* aemb = (const float*)d_in[4];
  const float* bemb = (const float*)d_in[5];
  const float* vnw = (const float*)d_in[6];
  const float* conv_w = (const float*)d_in[7];
  const float* conv_b = (const float*)d_in[8];
  const float* ngamma = (const float*)d_in[9];
  const float* nbeta = (const float*)d_in[10];
  const float* vn_w = (const float*)d_in[11];
  const float* vn_b = (const float*)d_in[12];
  const float* vn_g = (const float*)d_in[13];
  const float* vn_be = (const float*)d_in[14];
  float* out = (float*)d_out;

  const size_t NODE = (size_t)Ncnt * Hc;
  const size_t GH = (size_t)Gcnt * Hc;
  const int nScanBlk = (Ncnt + 255) / 256;  // 586

  size_t off = 0;
  char* base = (char*)d_ws;
  auto take = [&](size_t bytes) { size_t o = off; off += (bytes + 15) & ~(size_t)15; return o; };
  float* vn = (float*)(base + take(GH * 4));
  float* vnt = (float*)(base + take(GH * 4));
  float* vnu = (float*)(base + take(GH * 4));
  float* vnv = (float*)(base + take(GH * 4));
  float* statsN = (float*)(base + take(2 * Hc * 4));
  float* statsV1 = (float*)(base + take(2 * Hc * 4));
  float* statsV2 = (float*)(base + take(2 * Hc * 4));
  float* scbN = (float*)(base + take(Hc * 4));
  float* bbbN = (float*)(base + take(Hc * 4));
  int* rowptr = (int*)(base + take((size_t)(Ncnt + 1) * 4));
  int* cursor = (int*)(base + take((size_t)Ncnt * 4));
  int2* erec = (int2*)(base + take((size_t)Ecnt * 8));
  int* bsum = (int*)(base + take((size_t)nScanBlk * 4));
  bf16* P = (bf16*)(base + take(NODE * 2));
  bf16* T = (bf16*)(base + take(NODE * 2));
  bf16* WhiC = (bf16*)(base + take((size_t)Lcnt * 65536 * 2));
  bf16* WloC = (bf16*)(base + take((size_t)Lcnt * 65536 * 2));
  const size_t NEED = off;
  if (ws_size < NEED) {
    k_zero<<<(int)((GH + 255) / 256), 256, 0, stream>>>(out, (int)GH);
    k_diag<<<1, 1, 0, stream>>>(out, 100000.f + (float)(ws_size / (1024.0 * 1024.0)));
    return;
  }

  const int eBlk = (Ecnt + 255) / 256;
  const int nWaveBlk = (Ncnt + 3) / 4;
  const int aggBlk = (Ncnt + 7) / 8;       // half-wave per node
  const int segBlk = (Ncnt + 255) / 256;
  const int ggN = (Ncnt + 63) / 64;        // 2344, 1-D (64-row blocks)
  const dim3 gv(Gcnt / 64, 4);
  const float invN = 1.f / Ncnt;
  const float invG = 1.f / Gcnt;

  // CSR build (parallel scan) + packed edge records
  k_zero_int<<<nScanBlk, 256, 0, stream>>>(cursor, Ncnt);
  k_count<<<eBlk, 256, 0, stream>>>(ei, cursor);
  k_scan1<<<nScanBlk, 256, 0, stream>>>(cursor, rowptr, bsum, Ncnt);
  k_scan2<<<1, 1024, 0, stream>>>(bsum, nScanBlk);
  k_scan3<<<nScanBlk, 256, 0, stream>>>(rowptr, cursor, bsum, Ncnt);
  k_scatter<<<eBlk, 256, 0, stream>>>(ei, ea, batch, cursor, erec);

  // conv weight prep (hi/lo, fragment-packed)
  k_prep_w<<<(Lcnt * 8192 + 255) / 256, 256, 0, stream>>>(conv_w, WhiC, WloC, Lcnt);

  // Encoders + conv0 (stats fused for layer-1 BN)
  k_atom_encode<<<nWaveBlk, 256, 0, stream>>>(x, aemb, vnw, P);
  k_init_vn<<<(int)(GH / 256), 256, 0, stream>>>(vn, vnt, vnw);
  k_agg<<<aggBlk, 256, 0, stream>>>(P, T, rowptr, erec, bemb, nullptr, nullptr, nullptr, nullptr);
  k_zero<<<2, 256, 0, stream>>>(statsN, 2 * Hc);
  k_gemm_mfma<<<ggN, 256, 0, stream>>>(T, WhiC, WloC, conv_b, nullptr, P, statsN, Ncnt);

  for (int l = 1; l < Lcnt; ++l) {
    int p = l - 1;
    // BN constants for this layer's node BN (also zeroes statsN for next GEMM)
    k_bnprep<<<1, 256, 0, stream>>>(statsN, ngamma + (size_t)p * Hc, nbeta + (size_t)p * Hc,
                                    scbN, bbbN, invN);
    // vnt already = vn (dual-store); add segsum(relu(bn(P)))
    k_seg_vn<<<segBlk, 256, 0, stream>>>(P, batch, vnt, scbN, bbbN);
    // zero both VN stats buffers (adjacent) in one launch
    k_zero<<<4, 256, 0, stream>>>(statsV1, 4 * Hc);
    // VN MLP j=0: vnu = vnt @ w0 + b0 (stats -> V1)
    k_gemm_f32<<<gv, 256, 0, stream>>>(vnt, vn_w + (size_t)(2 * p) * 65536,
                                       vn_b + (size_t)(2 * p) * Hc, vnu, statsV1,
                                       nullptr, nullptr, nullptr, invG, Gcnt);
    // VN MLP j=1: vnv = relu(bnV1(vnu)) @ w1 + b1 (stats -> V2)
    k_gemm_f32<<<gv, 256, 0, stream>>>(vnu, vn_w + (size_t)(2 * p + 1) * 65536,
                                       vn_b + (size_t)(2 * p + 1) * Hc, vnv, statsV2,
                                       statsV1, vn_g + (size_t)(2 * p) * Hc,
                                       vn_be + (size_t)(2 * p) * Hc, invG, Gcnt);
    // vn = relu(bnV2(vnv)); also seeds vnt for next layer
    k_vn_relu<<<(int)(GH / 256), 256, 0, stream>>>(vnv, vn, vnt, statsV2,
                                                   vn_g + (size_t)(2 * p + 1) * Hc,
                                                   vn_be + (size_t)(2 * p + 1) * Hc, invG);
    // T = h2 + agg(h2), h2 = relu(bn(P)) + vn[batch]
    k_agg<<<aggBlk, 256, 0, stream>>>(P, T, rowptr, erec, bemb, vn, batch, scbN, bbbN);
    // P = T @ W + bias + P (stats fused for next BN; statsN was zeroed by k_bnprep)
    k_gemm_mfma<<<ggN, 256, 0, stream>>>(T, WhiC + (size_t)l * 65536, WloC + (size_t)l * 65536,
                                         conv_b + (size_t)l * Hc, P, P, statsN, Ncnt);
  }

  // Final BN + global add pool
  k_bnprep<<<1, 256, 0, stream>>>(statsN, ngamma + (size_t)(Lcnt - 1) * Hc,
                                  nbeta + (size_t)(Lcnt - 1) * Hc, scbN, bbbN, invN);
  k_zero<<<(int)((GH + 255) / 256), 256, 0, stream>>>(out, (int)GH);
  k_bn_pool<<<segBlk, 256, 0, stream>>>(P, batch, out, scbN, bbbN);
}